// Round 2
// baseline (1233.297 us; speedup 1.0000x reference)
//
#include <hip/hip_runtime.h>

#define B_TOT 16384
#define RR 32
#define NBLK (B_TOT / RR)
#define TT 30
#define LL 100
#define DTC 0.03f

__device__ __forceinline__ float rcpf(float x) { return __builtin_amdgcn_rcpf(x); }
__device__ __forceinline__ float sigm(float x) { return rcpf(1.f + __expf(-x)); }
__device__ __forceinline__ float tanh_(float x) {
    x = fminf(fmaxf(x, -15.f), 15.f);
    float e = __expf(2.f * x);
    return (e - 1.f) * rcpf(e + 1.f);
}
__device__ __forceinline__ float leaky(float x) { return x >= 0.f ? x : 0.01f * x; }

// gates[r] += sum_k h[r][k]*w[k], h transposed in LDS: sHT[k*36 + r]
__device__ __forceinline__ void gemm_ht(const float* sHT, const float* w, float* acc) {
#pragma unroll
    for (int k = 0; k < 64; ++k) {
        float wk = w[k];
        const float4* hp = (const float4*)(sHT + k * 36);
#pragma unroll
        for (int r4 = 0; r4 < 8; ++r4) {
            float4 hv = hp[r4];
            acc[4 * r4 + 0] = fmaf(hv.x, wk, acc[4 * r4 + 0]);
            acc[4 * r4 + 1] = fmaf(hv.y, wk, acc[4 * r4 + 1]);
            acc[4 * r4 + 2] = fmaf(hv.z, wk, acc[4 * r4 + 2]);
            acc[4 * r4 + 3] = fmaf(hv.w, wk, acc[4 * r4 + 3]);
        }
    }
}

__device__ __forceinline__ void lstm_update(const float* sG, float* sHT, float* creg,
                                            int urow, int j0) {
    const float* gr = sG + urow * 258;
#pragma unroll
    for (int u = 0; u < 8; ++u) {
        int j = j0 + u;
        float ig = gr[j];
        float fg = gr[j + 64];
        float gg = gr[j + 128];
        float og = gr[j + 192];
        float cc = sigm(fg) * creg[u] + sigm(ig) * tanh_(gg);
        creg[u] = cc;
        sHT[j * 36 + urow] = sigm(og) * tanh_(cc);
    }
}

__global__ __launch_bounds__(256, 2) void vae_lstm_kernel(
    const float* __restrict__ expert, const float* __restrict__ init_state,
    const float* __restrict__ eps,
    const float* __restrict__ W_se, const float* __restrict__ b_se,
    const float* __restrict__ W_ih_e, const float* __restrict__ W_hh_e,
    const float* __restrict__ b_ih_e, const float* __restrict__ b_hh_e,
    const float* __restrict__ mean_Ws, const float* __restrict__ mean_bs,
    const float* __restrict__ mean_Wf, const float* __restrict__ mean_bf,
    const float* __restrict__ lv_Ws, const float* __restrict__ lv_bs,
    const float* __restrict__ lv_Wf, const float* __restrict__ lv_bf,
    const float* __restrict__ W_init, const float* __restrict__ b_init,
    const float* __restrict__ W_ih_d, const float* __restrict__ W_hh_d,
    const float* __restrict__ b_ih_d, const float* __restrict__ b_hh_d,
    const float* __restrict__ W_c, const float* __restrict__ b_c,
    float* __restrict__ out_recons, float* __restrict__ out_mu, float* __restrict__ out_lv)
{
    const int tid = threadIdx.x;
    const int b0 = blockIdx.x * RR;

    // 9216 B persistent sHT + 56064 B phase region = 65280 B (< 64 KiB limit)
    __shared__ __align__(16) char smem[65280];
    float* sHT = (float*)smem;              // [64][36] fp32, h transposed (pad 36)
    float* RF = (float*)(smem + 9216);      // phase region, 14016 floats

    // ---- fold input matrices into registers: me = W_ih_e @ W_se (row tid), etc.
    float me[4] = {0.f, 0.f, 0.f, 0.f}, md[4] = {0.f, 0.f, 0.f, 0.f};
    float be, bd;
    {
        float bea = 0.f, bda = 0.f;
        for (int e = 0; e < 64; ++e) {
            float s0 = W_se[e * 4 + 0];
            float s1 = W_se[e * 4 + 1];
            float s2 = W_se[e * 4 + 2];
            float s3 = W_se[e * 4 + 3];
            float bs = b_se[e];
            float wie = W_ih_e[tid * 64 + e];
            float wid = W_ih_d[tid * 64 + e];
            me[0] = fmaf(wie, s0, me[0]); me[1] = fmaf(wie, s1, me[1]);
            me[2] = fmaf(wie, s2, me[2]); me[3] = fmaf(wie, s3, me[3]);
            md[0] = fmaf(wid, s0, md[0]); md[1] = fmaf(wid, s1, md[1]);
            md[2] = fmaf(wid, s2, md[2]); md[3] = fmaf(wid, s3, md[3]);
            bea = fmaf(wie, bs, bea);
            bda = fmaf(wid, bs, bda);
        }
        be = bea + b_ih_e[tid] + b_hh_e[tid];
        bd = bda + b_ih_d[tid] + b_hh_d[tid];
    }

    // ---- W_hh_e column (gate row tid) into registers
    float w[64];
    {
        const float4* p = (const float4*)(W_hh_e + tid * 64);
#pragma unroll
        for (int i = 0; i < 16; ++i) {
            float4 u = p[i];
            w[4 * i + 0] = u.x; w[4 * i + 1] = u.y; w[4 * i + 2] = u.z; w[4 * i + 3] = u.w;
        }
    }

    const int urow = tid >> 3;        // update-phase row
    const int j0 = (tid & 7) << 3;    // update-phase j-octet base
    float creg[8];
#pragma unroll
    for (int u = 0; u < 8; ++u) creg[u] = 0.f;

    // ---- encoder input staging: raw -> rel
    {
        float* sInp = RF;                    // [32][30][4] = 3840 floats
        float* sRaw = RF + 3840;             // 3840 floats
        for (int idx = tid; idx < RR * TT * 4; idx += 256)
            sRaw[idx] = expert[b0 * (TT * 4) + idx];
        for (int idx = tid; idx < 64 * 36; idx += 256) sHT[idx] = 0.f;
        __syncthreads();
        for (int idx = tid; idx < RR * TT * 4; idx += 256) {
            int q = idx % (TT * 4);
            int k = q & 3, t = q >> 2;
            float v = sRaw[idx];
            if (k < 2 && t > 0) v -= sRaw[idx - 4];
            sInp[idx] = v;
        }
        __syncthreads();
    }

    // ---- encoder: 30 LSTM steps
    {
        float* sInp = RF;
        float* sGates = RF + 3840;           // [32][258] = 8256 floats
        for (int stp = 0; stp < TT; ++stp) {
            float acc[32];
#pragma unroll
            for (int r = 0; r < 32; ++r) {
                const float* ip = sInp + (r * TT + stp) * 4;
                acc[r] = be + ip[0] * me[0] + ip[1] * me[1] + ip[2] * me[2] + ip[3] * me[3];
            }
            gemm_ht(sHT, w, acc);
#pragma unroll
            for (int r = 0; r < 32; ++r) sGates[r * 258 + tid] = acc[r];
            __syncthreads();
            lstm_update(sGates, sHT, creg, urow, j0);
            __syncthreads();
        }
    }

    // ---- MLP phase layout (floats within RF)
    float* sX = RF;                    // [32][64] = 2048
    float* sY = RF + 2048;             // [32][64] = 2048
    float* sWT = RF + 4096;            // up to 6600 floats (stride-padded transposed W)
    float* sMu = RF + 10696;           // [32][100] = 3200  (ends 13896 <= 14016)

    // copy hT -> sX[row][k]
    for (int idx = tid; idx < 2048; idx += 256) {
        int row = idx >> 6, k = idx & 63;
        sX[idx] = sHT[k * 36 + row];
    }
    __syncthreads();

    const int mj = tid & 63;
    const int mrg = tid >> 6;

    // hidden layer: out[row][j] = leaky(in[row]·W[j] + b[j]); W 64x64 fp32 global
    auto hidden_layer = [&](const float* in, float* outb, const float* Wg, const float* bg) {
        for (int idx = tid; idx < 4096; idx += 256) {
            int j = idx >> 6, k = idx & 63;
            sWT[k * 66 + j] = Wg[idx];          // transposed, stride 66
        }
        __syncthreads();
        float bj = bg[mj];
#pragma unroll
        for (int m = 0; m < 8; ++m) {
            int row = mrg * 8 + m;
            float a = bj;
            for (int k = 0; k < 64; ++k)
                a = fmaf(in[row * 64 + k], sWT[k * 66 + mj], a);
            outb[row * 64 + mj] = leaky(a);
        }
        __syncthreads();
    };

    // final layer: 100 outputs; mode 0: write mu (LDS+global); mode 1: write lv global,
    // fuse z = tanh(eps*exp(0.5*lv)+mu) into sMu.
    auto final_layer = [&](const float* in, float* outg, const float* Wg, const float* bg,
                           int fuse_z) {
        for (int idx = tid; idx < 6400; idx += 256) {
            int l = idx >> 6, k = idx & 63;
            sWT[k * 102 + l] = Wg[idx];
        }
        __syncthreads();
        for (int idx = tid; idx < RR * LL; idx += 256) {
            int row = idx / LL, l = idx - row * LL;
            float a = bg[l];
            for (int k = 0; k < 64; ++k)
                a = fmaf(in[row * 64 + k], sWT[k * 102 + l], a);
            a = leaky(a);
            outg[(size_t)(b0 + row) * LL + l] = a;
            if (fuse_z) {
                float ev = eps[(size_t)(b0 + row) * LL + l];
                sMu[idx] = tanh_(fmaf(ev, __expf(0.5f * a), sMu[idx]));
            } else {
                sMu[idx] = a;
            }
        }
        __syncthreads();
    };

    // mean path
    hidden_layer(sX, sY, mean_Ws, mean_bs);
    hidden_layer(sY, sX, mean_Ws + 4096, mean_bs + 64);
    hidden_layer(sX, sY, mean_Ws + 8192, mean_bs + 128);
    final_layer(sY, out_mu, mean_Wf, mean_bf, 0);

    // logvar path (re-copy h); z fused into sMu in its final layer
    for (int idx = tid; idx < 2048; idx += 256) {
        int row = idx >> 6, k = idx & 63;
        sX[idx] = sHT[k * 36 + row];
    }
    hidden_layer(sX, sY, lv_Ws, lv_bs);
    hidden_layer(sY, sX, lv_Ws + 4096, lv_bs + 64);
    hidden_layer(sX, sY, lv_Ws + 8192, lv_bs + 128);
    final_layer(sY, out_lv, lv_Wf, lv_bf, 1);

    // dh = z @ W_init.T + b_init -> sHT (h = c = dh); z is in sMu
    {
        for (int idx = tid; idx < 6400; idx += 256) {
            int j = idx / LL, l = idx - j * LL;
            sWT[l * 66 + j] = W_init[idx];      // W_init is (64,100); transposed stride 66
        }
        __syncthreads();
        float bi = b_init[mj];
#pragma unroll
        for (int m = 0; m < 8; ++m) {
            int row = mrg * 8 + m;
            float a = bi;
            for (int l = 0; l < LL; ++l)
                a = fmaf(sMu[row * LL + l], sWT[l * 66 + mj], a);
            sHT[mj * 36 + row] = a;
        }
        __syncthreads();
#pragma unroll
        for (int u = 0; u < 8; ++u) creg[u] = sHT[(j0 + u) * 36 + urow];
    }

    // ---- decoder layout
    float* sGd = RF;                 // [32][258] = 8256 floats
    float* sPrev = RF + 8320;        // [32][4] = 128
    float* sWc = RF + 8448;          // [2][64] = 128
    float* sCtrl = RF + 8576;        // [32][2] = 64

    if (tid < 128) sWc[tid] = W_c[tid];
    if (tid < 128) sPrev[tid] = init_state[b0 * 4 + tid];
    {
        const float4* p = (const float4*)(W_hh_d + tid * 64);
#pragma unroll
        for (int i = 0; i < 16; ++i) {
            float4 u = p[i];
            w[4 * i + 0] = u.x; w[4 * i + 1] = u.y; w[4 * i + 2] = u.z; w[4 * i + 3] = u.w;
        }
    }
    __syncthreads();

    // ---- decoder: 30 steps
    for (int stp = 0; stp < TT; ++stp) {
        float acc[32];
#pragma unroll
        for (int r = 0; r < 32; ++r) {
            const float* pv = sPrev + r * 4;
            acc[r] = bd + pv[0] * md[0] + pv[1] * md[1] + pv[2] * md[2] + pv[3] * md[3];
        }
        gemm_ht(sHT, w, acc);
#pragma unroll
        for (int r = 0; r < 32; ++r) sGd[r * 258 + tid] = acc[r];
        __syncthreads();
        lstm_update(sGd, sHT, creg, urow, j0);
        __syncthreads();
        if (tid < 64) {
            int row = tid & 31, which = tid >> 5;
            float a = b_c[which];
            for (int k = 0; k < 64; ++k)
                a = fmaf(sHT[k * 36 + row], sWc[which * 64 + k], a);
            sCtrl[row * 2 + which] = a;
        }
        __syncthreads();
        if (tid < 32) {
            int row = tid;
            float pedal = sCtrl[row * 2];
            float steer = fminf(fmaxf(sCtrl[row * 2 + 1], -0.5f), 0.5f);
            float x = sPrev[row * 4 + 0], y = sPrev[row * 4 + 1];
            float psi = sPrev[row * 4 + 2], v = sPrev[row * 4 + 3];
            float v1 = fminf(fmaxf(v + pedal * DTC, 0.f), 30.f);
            float sn, cs;
            __sincosf(psi, &sn, &cs);
            float psid = fminf(fmaxf(v * __tanf(steer) * 0.4f, -1.57f), 1.57f);
            float nx = fmaf(v * cs, DTC, x);
            float ny = fmaf(v * sn, DTC, y);
            float npsi = fmaf(psid, DTC, psi);
            sPrev[row * 4 + 0] = nx; sPrev[row * 4 + 1] = ny;
            sPrev[row * 4 + 2] = npsi; sPrev[row * 4 + 3] = v1;
            float4 o; o.x = nx; o.y = ny; o.z = npsi; o.w = v1;
            *(float4*)(out_recons + ((size_t)(b0 + row) * TT + stp) * 4) = o;
        }
        __syncthreads();
    }
}

extern "C" void kernel_launch(void* const* d_in, const int* in_sizes, int n_in,
                              void* d_out, int out_size, void* d_ws, size_t ws_size,
                              hipStream_t stream) {
    (void)in_sizes; (void)n_in; (void)ws_size; (void)d_ws; (void)out_size;
    const float* expert    = (const float*)d_in[0];
    const float* init_st   = (const float*)d_in[1];
    const float* eps       = (const float*)d_in[2];
    const float* W_se      = (const float*)d_in[3];
    const float* b_se      = (const float*)d_in[4];
    const float* W_ih_e    = (const float*)d_in[5];
    const float* W_hh_e    = (const float*)d_in[6];
    const float* b_ih_e    = (const float*)d_in[7];
    const float* b_hh_e    = (const float*)d_in[8];
    const float* mean_Ws   = (const float*)d_in[9];
    const float* mean_bs   = (const float*)d_in[10];
    const float* mean_Wf   = (const float*)d_in[11];
    const float* mean_bf   = (const float*)d_in[12];
    const float* lv_Ws     = (const float*)d_in[13];
    const float* lv_bs     = (const float*)d_in[14];
    const float* lv_Wf     = (const float*)d_in[15];
    const float* lv_bf     = (const float*)d_in[16];
    const float* W_init    = (const float*)d_in[17];
    const float* b_init    = (const float*)d_in[18];
    const float* W_ih_d    = (const float*)d_in[19];
    const float* W_hh_d    = (const float*)d_in[20];
    const float* b_ih_d    = (const float*)d_in[21];
    const float* b_hh_d    = (const float*)d_in[22];
    const float* W_c       = (const float*)d_in[23];
    const float* b_c       = (const float*)d_in[24];

    float* out = (float*)d_out;
    const size_t n_traj = (size_t)B_TOT * TT * 4;       // 1,966,080
    const size_t n_lat  = (size_t)B_TOT * LL;           // 1,638,400
    float* out_recons = out;
    float* out_expert = out + n_traj;
    float* out_mu     = out + 2 * n_traj;
    float* out_lv     = out + 2 * n_traj + n_lat;

    // expert_traj passthrough
    hipMemcpyAsync(out_expert, d_in[0], n_traj * sizeof(float),
                   hipMemcpyDeviceToDevice, stream);

    vae_lstm_kernel<<<NBLK, 256, 0, stream>>>(
        expert, init_st, eps, W_se, b_se, W_ih_e, W_hh_e, b_ih_e, b_hh_e,
        mean_Ws, mean_bs, mean_Wf, mean_bf, lv_Ws, lv_bs, lv_Wf, lv_bf,
        W_init, b_init, W_ih_d, W_hh_d, b_ih_d, b_hh_d, W_c, b_c,
        out_recons, out_mu, out_lv);
}

// Round 3
// 287.770 us; speedup vs baseline: 4.2857x; 4.2857x over previous
//
#include <hip/hip_runtime.h>

typedef unsigned short u16;
typedef unsigned int u32;
typedef __attribute__((ext_vector_type(8))) short bf16x8;   // 8 bf16 in 4 VGPRs
typedef __attribute__((ext_vector_type(4))) float f32x4;

#define B_TOT 16384
#define RR 32
#define NBLK (B_TOT / RR)
#define TT 30
#define LL 100
#define DTC 0.03f

// ---- LDS offsets (bytes), total 52736 ----
#define OFF_H     0        // u16 [2][32][72]  = 9216  (h double-buffer, A-layout, pad 72)
#define OFF_XB    9216     // u16 [2][32][72]  = 9216  (MLP bufs; aliases sRaw@staging, sPrev/sWc@decoder)
#define OFF_Z     18432    // u16 [32][136]    = 8704  (z bf16, K-padded to 128, stride 136)
#define OFF_INP   27136    // f32 [32][30][4]  = 15360 (encoder inputs; aliases muBuf f32[32][100])
#define OFF_FE    42496    // f32 [256][5]     = 5120  (folded enc input proj: me[4], bias)
#define OFF_FD    47616    // f32 [256][5]     = 5120  (folded dec input proj)
#define SMEM_SZ   52736

__device__ __forceinline__ float bf2f(u16 u) {
    union { u32 i; float f; } v; v.i = ((u32)u) << 16; return v.f;
}
__device__ __forceinline__ u16 f2bf(float f) {
    union { float f; u32 i; } v; v.f = f;
    return (u16)((v.i + 0x7FFFu + ((v.i >> 16) & 1u)) >> 16);
}
__device__ __forceinline__ float rcpf(float x) { return __builtin_amdgcn_rcpf(x); }
__device__ __forceinline__ float sigm(float x) { return rcpf(1.f + __expf(-x)); }
__device__ __forceinline__ float tanh_(float x) {
    x = fminf(fmaxf(x, -15.f), 15.f);
    float e = __expf(2.f * x);
    return (e - 1.f) * rcpf(e + 1.f);
}
__device__ __forceinline__ float leaky(float x) { return x >= 0.f ? x : 0.01f * x; }

__device__ __forceinline__ f32x4 mfma16(bf16x8 a, bf16x8 b, f32x4 c) {
    return __builtin_amdgcn_mfma_f32_16x16x32_bf16(a, b, c, 0, 0, 0);
}
__device__ __forceinline__ bf16x8 packw(const float* p) {
    bf16x8 r;
#pragma unroll
    for (int j = 0; j < 8; ++j) r[j] = (short)f2bf(p[j]);
    return r;
}

struct LstmRegs {
    float fe[4][4];   // folded input-proj rows for the 4 gate columns this lane owns
    float beg[4];     // folded biases
    bf16x8 bw[4][2];  // W_hh B-fragments: [gate][Ktile]
};

__device__ __forceinline__ void load_fold(const float* fold, int jcol, LstmRegs& R) {
#pragma unroll
    for (int g = 0; g < 4; ++g) {
        const float* fp = fold + (g * 64 + jcol) * 5;
        R.fe[g][0] = fp[0]; R.fe[g][1] = fp[1]; R.fe[g][2] = fp[2]; R.fe[g][3] = fp[3];
        R.beg[g] = fp[4];
    }
}
__device__ __forceinline__ void load_whh(const float* Wg, int jcol, int quad, LstmRegs& R) {
#pragma unroll
    for (int g = 0; g < 4; ++g)
#pragma unroll
        for (int kt = 0; kt < 2; ++kt)
            R.bw[g][kt] = packw(Wg + (g * 64 + jcol) * 64 + kt * 32 + quad * 8);
}

// One LSTM step. Hc: current h (A-layout bf16, stride 72). Hn: next h.
// ip for batch-row m lives at ipbase + m*iprstride (4 consecutive floats).
__device__ __forceinline__ void lstm_step(const u16* Hc, u16* Hn,
                                          const float* ipbase, int iprstride,
                                          const LstmRegs& R, float* creg,
                                          int lcol, int quad, int jcol) {
    f32x4 acc[2][4];
#pragma unroll
    for (int Mt = 0; Mt < 2; ++Mt)
#pragma unroll
        for (int r = 0; r < 4; ++r) {
            int m = Mt * 16 + quad * 4 + r;
            f32x4 ip = *(const f32x4*)(ipbase + m * iprstride);
#pragma unroll
            for (int g = 0; g < 4; ++g)
                acc[Mt][g][r] = R.beg[g] + ip[0] * R.fe[g][0] + ip[1] * R.fe[g][1]
                              + ip[2] * R.fe[g][2] + ip[3] * R.fe[g][3];
        }
    bf16x8 a[2][2];
#pragma unroll
    for (int Mt = 0; Mt < 2; ++Mt)
#pragma unroll
        for (int kt = 0; kt < 2; ++kt)
            a[Mt][kt] = *(const bf16x8*)(Hc + (Mt * 16 + lcol) * 72 + kt * 32 + quad * 8);
#pragma unroll
    for (int Mt = 0; Mt < 2; ++Mt)
#pragma unroll
        for (int g = 0; g < 4; ++g) {
            acc[Mt][g] = mfma16(a[Mt][0], R.bw[g][0], acc[Mt][g]);
            acc[Mt][g] = mfma16(a[Mt][1], R.bw[g][1], acc[Mt][g]);
        }
#pragma unroll
    for (int Mt = 0; Mt < 2; ++Mt)
#pragma unroll
        for (int r = 0; r < 4; ++r) {
            float ig = acc[Mt][0][r], fg = acc[Mt][1][r];
            float gg = acc[Mt][2][r], og = acc[Mt][3][r];
            float c = sigm(fg) * creg[Mt * 4 + r] + sigm(ig) * tanh_(gg);
            creg[Mt * 4 + r] = c;
            float h = sigm(og) * tanh_(c);
            Hn[(Mt * 16 + quad * 4 + r) * 72 + jcol] = f2bf(h);
        }
}

__global__ __launch_bounds__(256, 2) void vae_lstm_kernel(
    const float* __restrict__ expert, const float* __restrict__ init_state,
    const float* __restrict__ eps,
    const float* __restrict__ W_se, const float* __restrict__ b_se,
    const float* __restrict__ W_ih_e, const float* __restrict__ W_hh_e,
    const float* __restrict__ b_ih_e, const float* __restrict__ b_hh_e,
    const float* __restrict__ mean_Ws, const float* __restrict__ mean_bs,
    const float* __restrict__ mean_Wf, const float* __restrict__ mean_bf,
    const float* __restrict__ lv_Ws, const float* __restrict__ lv_bs,
    const float* __restrict__ lv_Wf, const float* __restrict__ lv_bf,
    const float* __restrict__ W_init, const float* __restrict__ b_init,
    const float* __restrict__ W_ih_d, const float* __restrict__ W_hh_d,
    const float* __restrict__ b_ih_d, const float* __restrict__ b_hh_d,
    const float* __restrict__ W_c, const float* __restrict__ b_c,
    float* __restrict__ out_recons, float* __restrict__ out_mu, float* __restrict__ out_lv)
{
    const int tid = threadIdx.x;
    const int b0g = blockIdx.x * RR;
    const int wv = tid >> 6;
    const int lane = tid & 63;
    const int lcol = lane & 15;        // MFMA col (A-row m / C-col n)
    const int quad = lane >> 4;        // MFMA quad
    const int jcol = wv * 16 + lcol;   // this lane's hidden/gate column

    __shared__ __align__(16) char smem[SMEM_SZ];
    u16* Hbuf  = (u16*)(smem + OFF_H);
    u16* XB0   = (u16*)(smem + OFF_XB);
    u16* XB1   = XB0 + 2304;
    u16* zBuf  = (u16*)(smem + OFF_Z);
    float* inp = (float*)(smem + OFF_INP);
    float* muBuf = (float*)(smem + OFF_INP);    // alias (inp dead after encoder)
    float* fold_e = (float*)(smem + OFF_FE);
    float* fold_d = (float*)(smem + OFF_FD);
    float* sRaw  = (float*)(smem + OFF_XB);     // alias (staging only)
    float* sPrev = (float*)(smem + OFF_XB);     // alias (decoder)
    float* sWc   = (float*)(smem + OFF_XB + 512);

    // ---- fold input projections: col n = tid ----
    {
        float me[4] = {0,0,0,0}, md[4] = {0,0,0,0};
        float bea = 0.f, bda = 0.f;
        for (int e = 0; e < 64; ++e) {
            float s0 = W_se[e*4+0], s1 = W_se[e*4+1], s2 = W_se[e*4+2], s3 = W_se[e*4+3];
            float bs = b_se[e];
            float wie = W_ih_e[tid*64+e], wid = W_ih_d[tid*64+e];
            me[0] = fmaf(wie,s0,me[0]); me[1] = fmaf(wie,s1,me[1]);
            me[2] = fmaf(wie,s2,me[2]); me[3] = fmaf(wie,s3,me[3]);
            md[0] = fmaf(wid,s0,md[0]); md[1] = fmaf(wid,s1,md[1]);
            md[2] = fmaf(wid,s2,md[2]); md[3] = fmaf(wid,s3,md[3]);
            bea = fmaf(wie,bs,bea); bda = fmaf(wid,bs,bda);
        }
        float* fp = fold_e + tid*5;
        fp[0]=me[0]; fp[1]=me[1]; fp[2]=me[2]; fp[3]=me[3];
        fp[4] = bea + b_ih_e[tid] + b_hh_e[tid];
        float* fq = fold_d + tid*5;
        fq[0]=md[0]; fq[1]=md[1]; fq[2]=md[2]; fq[3]=md[3];
        fq[4] = bda + b_ih_d[tid] + b_hh_d[tid];
    }

    // ---- staging: raw expert -> rel inp; zero H[0] ----
    for (int idx = tid; idx < RR*TT*4; idx += 256)
        sRaw[idx] = expert[b0g*(TT*4) + idx];
    for (int idx = tid; idx < 1152; idx += 256) ((u32*)Hbuf)[idx] = 0;
    __syncthreads();
    for (int idx = tid; idx < RR*TT*4; idx += 256) {
        int q = idx % (TT*4);
        int k = q & 3, t = q >> 2;
        float v = sRaw[idx];
        if (k < 2 && t > 0) v -= sRaw[idx - 4];
        int m = idx / (TT*4);
        inp[(m*TT + t)*4 + k] = v;
    }
    __syncthreads();

    LstmRegs R;
    float creg[8];
#pragma unroll
    for (int u = 0; u < 8; ++u) creg[u] = 0.f;

    // ---- encoder: 30 MFMA LSTM steps, 1 barrier each ----
    load_fold(fold_e, jcol, R);
    load_whh(W_hh_e, jcol, quad, R);
    for (int stp = 0; stp < TT; ++stp) {
        const u16* Hc = Hbuf + (stp & 1) * 2304;
        u16* Hn = Hbuf + ((stp + 1) & 1) * 2304;
        lstm_step(Hc, Hn, inp + stp * 4, TT * 4, R, creg, lcol, quad, jcol);
        __syncthreads();
    }
    // hT now in Hbuf[0] (A-layout)

    // zero zBuf (pad area must be 0 for the W_init matmul)
    {
        u32* zb = (u32*)zBuf;
        for (int idx = tid; idx < 2176; idx += 256) zb[idx] = 0;
    }

    // ---- MLP machinery ----
    auto mlp_hidden = [&](const u16* inB, u16* outB, const float* Wg, const float* bg) {
        float bv = bg[jcol];
        bf16x8 bb0 = packw(Wg + jcol*64 + quad*8);
        bf16x8 bb1 = packw(Wg + jcol*64 + 32 + quad*8);
        f32x4 acc[2];
#pragma unroll
        for (int Mt = 0; Mt < 2; ++Mt) {
            acc[Mt][0]=bv; acc[Mt][1]=bv; acc[Mt][2]=bv; acc[Mt][3]=bv;
            bf16x8 a0 = *(const bf16x8*)(inB + (Mt*16+lcol)*72 + quad*8);
            bf16x8 a1 = *(const bf16x8*)(inB + (Mt*16+lcol)*72 + 32 + quad*8);
            acc[Mt] = mfma16(a0, bb0, acc[Mt]);
            acc[Mt] = mfma16(a1, bb1, acc[Mt]);
        }
#pragma unroll
        for (int Mt = 0; Mt < 2; ++Mt)
#pragma unroll
            for (int r = 0; r < 4; ++r)
                outB[(Mt*16+quad*4+r)*72 + jcol] = f2bf(leaky(acc[Mt][r]));
        __syncthreads();
    };

    auto mlp_final = [&](const u16* inB, const float* Wg, const float* bg, int mode) {
        for (int nt = wv; nt < 7; nt += 4) {
            int n = nt * 16 + lcol;
            bool ok = (n < LL);
            float bv = ok ? bg[n] : 0.f;
            bf16x8 bb0, bb1;
            if (ok) {
                bb0 = packw(Wg + n*64 + quad*8);
                bb1 = packw(Wg + n*64 + 32 + quad*8);
            } else {
#pragma unroll
                for (int j = 0; j < 8; ++j) { bb0[j] = 0; bb1[j] = 0; }
            }
            f32x4 acc[2];
#pragma unroll
            for (int Mt = 0; Mt < 2; ++Mt) {
                acc[Mt][0]=bv; acc[Mt][1]=bv; acc[Mt][2]=bv; acc[Mt][3]=bv;
                bf16x8 a0 = *(const bf16x8*)(inB + (Mt*16+lcol)*72 + quad*8);
                bf16x8 a1 = *(const bf16x8*)(inB + (Mt*16+lcol)*72 + 32 + quad*8);
                acc[Mt] = mfma16(a0, bb0, acc[Mt]);
                acc[Mt] = mfma16(a1, bb1, acc[Mt]);
            }
            if (ok) {
#pragma unroll
                for (int Mt = 0; Mt < 2; ++Mt)
#pragma unroll
                    for (int r = 0; r < 4; ++r) {
                        int m = Mt*16 + quad*4 + r;
                        float vv = leaky(acc[Mt][r]);
                        size_t gi = (size_t)(b0g + m) * LL + n;
                        if (mode == 0) {
                            muBuf[m*LL + n] = vv;
                            out_mu[gi] = vv;
                        } else {
                            out_lv[gi] = vv;
                            float zv = tanh_(fmaf(eps[gi], __expf(0.5f * vv), muBuf[m*LL + n]));
                            zBuf[m*136 + n] = f2bf(zv);
                        }
                    }
            }
        }
        __syncthreads();
    };

    // mean path (hT stays intact in Hbuf[0])
    mlp_hidden(Hbuf, XB0, mean_Ws, mean_bs);
    mlp_hidden(XB0, XB1, mean_Ws + 4096, mean_bs + 64);
    mlp_hidden(XB1, XB0, mean_Ws + 8192, mean_bs + 128);
    mlp_final(XB0, mean_Wf, mean_bf, 0);
    // logvar path + fused reparameterization into zBuf
    mlp_hidden(Hbuf, XB0, lv_Ws, lv_bs);
    mlp_hidden(XB0, XB1, lv_Ws + 4096, lv_bs + 64);
    mlp_hidden(XB1, XB0, lv_Ws + 8192, lv_bs + 128);
    mlp_final(XB0, lv_Wf, lv_bf, 1);

    // ---- dh = z @ W_init^T + b_init  -> Hbuf[0] (h) and creg (c, fp32) ----
    {
        float bv = b_init[jcol];
        bf16x8 bi[4];
#pragma unroll
        for (int kt = 0; kt < 3; ++kt)
            bi[kt] = packw(W_init + jcol*LL + kt*32 + quad*8);
        {
            float f[8];
#pragma unroll
            for (int j = 0; j < 8; ++j) {
                int k = 96 + quad*8 + j;
                f[j] = (k < LL) ? W_init[jcol*LL + k] : 0.f;
            }
            bi[3] = packw(f);
        }
        f32x4 acc[2];
#pragma unroll
        for (int Mt = 0; Mt < 2; ++Mt) {
            acc[Mt][0]=bv; acc[Mt][1]=bv; acc[Mt][2]=bv; acc[Mt][3]=bv;
#pragma unroll
            for (int kt = 0; kt < 4; ++kt) {
                bf16x8 az = *(const bf16x8*)(zBuf + (Mt*16+lcol)*136 + kt*32 + quad*8);
                acc[Mt] = mfma16(az, bi[kt], acc[Mt]);
            }
#pragma unroll
            for (int r = 0; r < 4; ++r) {
                creg[Mt*4 + r] = acc[Mt][r];
                Hbuf[(Mt*16+quad*4+r)*72 + jcol] = f2bf(acc[Mt][r]);
            }
        }
    }

    // ---- decoder prep ----
    load_fold(fold_d, jcol, R);
    load_whh(W_hh_d, jcol, quad, R);
    if (tid < 128) sPrev[tid] = init_state[b0g*4 + tid];
    if (tid < 128) sWc[tid] = W_c[tid];
    float bc0 = b_c[0], bc1 = b_c[1];
    __syncthreads();

    // ---- decoder: 30 steps ----
    for (int stp = 0; stp < TT; ++stp) {
        const u16* Hc = Hbuf + (stp & 1) * 2304;
        u16* Hn = Hbuf + ((stp + 1) & 1) * 2304;
        lstm_step(Hc, Hn, sPrev, 4, R, creg, lcol, quad, jcol);
        __syncthreads();
        if (tid < 32) {
            int row = tid;
            const u16* hr = Hn + row * 72;
            float a0 = bc0, a1 = bc1;
#pragma unroll
            for (int k = 0; k < 64; ++k) {
                float hv = bf2f(hr[k]);
                a0 = fmaf(hv, sWc[k], a0);
                a1 = fmaf(hv, sWc[64 + k], a1);
            }
            float pedal = a0;
            float steer = fminf(fmaxf(a1, -0.5f), 0.5f);
            float x = sPrev[row*4+0], y = sPrev[row*4+1];
            float psi = sPrev[row*4+2], v = sPrev[row*4+3];
            float v1 = fminf(fmaxf(v + pedal * DTC, 0.f), 30.f);
            float sn, cs;
            __sincosf(psi, &sn, &cs);
            float psid = fminf(fmaxf(v * __tanf(steer) * 0.4f, -1.57f), 1.57f);
            float nx = fmaf(v * cs, DTC, x);
            float ny = fmaf(v * sn, DTC, y);
            float npsi = fmaf(psid, DTC, psi);
            sPrev[row*4+0] = nx; sPrev[row*4+1] = ny;
            sPrev[row*4+2] = npsi; sPrev[row*4+3] = v1;
            float4 o; o.x = nx; o.y = ny; o.z = npsi; o.w = v1;
            *(float4*)(out_recons + ((size_t)(b0g + row) * TT + stp) * 4) = o;
        }
        __syncthreads();
    }
}

extern "C" void kernel_launch(void* const* d_in, const int* in_sizes, int n_in,
                              void* d_out, int out_size, void* d_ws, size_t ws_size,
                              hipStream_t stream) {
    (void)in_sizes; (void)n_in; (void)ws_size; (void)d_ws; (void)out_size;
    const float* expert    = (const float*)d_in[0];
    const float* init_st   = (const float*)d_in[1];
    const float* eps       = (const float*)d_in[2];
    const float* W_se      = (const float*)d_in[3];
    const float* b_se      = (const float*)d_in[4];
    const float* W_ih_e    = (const float*)d_in[5];
    const float* W_hh_e    = (const float*)d_in[6];
    const float* b_ih_e    = (const float*)d_in[7];
    const float* b_hh_e    = (const float*)d_in[8];
    const float* mean_Ws   = (const float*)d_in[9];
    const float* mean_bs   = (const float*)d_in[10];
    const float* mean_Wf   = (const float*)d_in[11];
    const float* mean_bf   = (const float*)d_in[12];
    const float* lv_Ws     = (const float*)d_in[13];
    const float* lv_bs     = (const float*)d_in[14];
    const float* lv_Wf     = (const float*)d_in[15];
    const float* lv_bf     = (const float*)d_in[16];
    const float* W_init    = (const float*)d_in[17];
    const float* b_init    = (const float*)d_in[18];
    const float* W_ih_d    = (const float*)d_in[19];
    const float* W_hh_d    = (const float*)d_in[20];
    const float* b_ih_d    = (const float*)d_in[21];
    const float* b_hh_d    = (const float*)d_in[22];
    const float* W_c       = (const float*)d_in[23];
    const float* b_c       = (const float*)d_in[24];

    float* out = (float*)d_out;
    const size_t n_traj = (size_t)B_TOT * TT * 4;
    const size_t n_lat  = (size_t)B_TOT * LL;
    float* out_recons = out;
    float* out_expert = out + n_traj;
    float* out_mu     = out + 2 * n_traj;
    float* out_lv     = out + 2 * n_traj + n_lat;

    hipMemcpyAsync(out_expert, d_in[0], n_traj * sizeof(float),
                   hipMemcpyDeviceToDevice, stream);

    vae_lstm_kernel<<<NBLK, 256, 0, stream>>>(
        expert, init_st, eps, W_se, b_se, W_ih_e, W_hh_e, b_ih_e, b_hh_e,
        mean_Ws, mean_bs, mean_Wf, mean_bf, lv_Ws, lv_bs, lv_Wf, lv_bf,
        W_init, b_init, W_ih_d, W_hh_d, b_ih_d, b_hh_d, W_c, b_c,
        out_recons, out_mu, out_lv);
}

// Round 4
// 245.736 us; speedup vs baseline: 5.0188x; 1.1711x over previous
//
#include <hip/hip_runtime.h>

typedef unsigned short u16;
typedef unsigned int u32;
typedef __attribute__((ext_vector_type(8))) short bf16x8;
typedef __attribute__((ext_vector_type(4))) float f32x4;

#define B_TOT 16384
#define RR 16
#define NBLK (B_TOT / RR)
#define TT 30
#define LL 100
#define DTC 0.03f

#define HST 104            // u16 stride of H rows (K=96 + pad); 16B-aligned rows
#define HBUF_U16 (RR * HST)  // 1664 u16 per buffer

// ---- LDS byte offsets, total 33024 ----
#define OFF_H   0          // u16 [2][16][104] = 6656
#define OFF_XB  6656       // u16 [2][16][72]  = 4608   (sRaw f32[1920]=7680B aliases XB+Z at staging)
#define OFF_Z   11264      // u16 [16][136]    = 4352
#define OFF_MU  15616      // f32 [16][100] = 6400 ; aliases inp bf16 [16][30][4] = 3840
#define OFF_FE  22016      // f32 [256][5] = 5120
#define OFF_FD  27136      // f32 [256][5] = 5120
#define OFF_PV  32256      // f32 [16][4] = 256
#define OFF_WC  32512      // f32 [2][64] = 512
#define SMEM_SZ 33024

__device__ __forceinline__ float bf2f(u16 u) {
    union { u32 i; float f; } v; v.i = ((u32)u) << 16; return v.f;
}
__device__ __forceinline__ u16 f2bf(float f) {
    union { float f; u32 i; } v; v.f = f;
    return (u16)((v.i + 0x7FFFu + ((v.i >> 16) & 1u)) >> 16);
}
__device__ __forceinline__ float rcpf(float x) { return __builtin_amdgcn_rcpf(x); }
__device__ __forceinline__ float tanh_(float x) {
    x = fminf(fmaxf(x, -15.f), 15.f);
    float e = __expf(2.f * x);
    return (e - 1.f) * rcpf(e + 1.f);
}
__device__ __forceinline__ float leaky(float x) { return x >= 0.f ? x : 0.01f * x; }
__device__ __forceinline__ f32x4 mfma16(bf16x8 a, bf16x8 b, f32x4 c) {
    return __builtin_amdgcn_mfma_f32_16x16x32_bf16(a, b, c, 0, 0, 0);
}
__device__ __forceinline__ bf16x8 packw(const float* p) {
    bf16x8 r;
#pragma unroll
    for (int j = 0; j < 8; ++j) r[j] = (short)f2bf(p[j]);
    return r;
}

__global__ __launch_bounds__(256, 4) void vae_lstm_kernel(
    const float* __restrict__ expert, const float* __restrict__ init_state,
    const float* __restrict__ eps,
    const float* __restrict__ W_se, const float* __restrict__ b_se,
    const float* __restrict__ W_ih_e, const float* __restrict__ W_hh_e,
    const float* __restrict__ b_ih_e, const float* __restrict__ b_hh_e,
    const float* __restrict__ mean_Ws, const float* __restrict__ mean_bs,
    const float* __restrict__ mean_Wf, const float* __restrict__ mean_bf,
    const float* __restrict__ lv_Ws, const float* __restrict__ lv_bs,
    const float* __restrict__ lv_Wf, const float* __restrict__ lv_bf,
    const float* __restrict__ W_init, const float* __restrict__ b_init,
    const float* __restrict__ W_ih_d, const float* __restrict__ W_hh_d,
    const float* __restrict__ b_ih_d, const float* __restrict__ b_hh_d,
    const float* __restrict__ W_c, const float* __restrict__ b_c,
    float* __restrict__ out_recons, float* __restrict__ out_expert,
    float* __restrict__ out_mu, float* __restrict__ out_lv)
{
    const int tid = threadIdx.x;
    const int b0g = blockIdx.x * RR;
    const int wv = tid >> 6;
    const int lane = tid & 63;
    const int lcol = lane & 15;       // MFMA n-col / A-row m
    const int quad = lane >> 4;
    const int jcol = wv * 16 + lcol;  // hidden column owned by this lane

    __shared__ __align__(16) char smem[SMEM_SZ];
    u16* Hbuf   = (u16*)(smem + OFF_H);
    u16* XB0    = (u16*)(smem + OFF_XB);
    u16* XB1    = XB0 + RR * 72;
    u16* zBuf   = (u16*)(smem + OFF_Z);
    float* muBuf = (float*)(smem + OFF_MU);
    u16* inp    = (u16*)(smem + OFF_MU);      // alias: dead before muBuf born
    float* fold_e = (float*)(smem + OFF_FE);
    float* fold_d = (float*)(smem + OFF_FD);
    float* sRaw  = (float*)(smem + OFF_XB);   // alias at staging only
    float* sPrev = (float*)(smem + OFF_PV);
    float* sWc   = (float*)(smem + OFF_WC);

    // ---- fold input projections (thread tid = gate column) ----
    {
        float me[4] = {0,0,0,0}, md[4] = {0,0,0,0};
        float bea = 0.f, bda = 0.f;
        for (int e = 0; e < 64; ++e) {
            float s0 = W_se[e*4+0], s1 = W_se[e*4+1], s2 = W_se[e*4+2], s3 = W_se[e*4+3];
            float bs = b_se[e];
            float wie = W_ih_e[tid*64+e], wid = W_ih_d[tid*64+e];
            me[0] = fmaf(wie,s0,me[0]); me[1] = fmaf(wie,s1,me[1]);
            me[2] = fmaf(wie,s2,me[2]); me[3] = fmaf(wie,s3,me[3]);
            md[0] = fmaf(wid,s0,md[0]); md[1] = fmaf(wid,s1,md[1]);
            md[2] = fmaf(wid,s2,md[2]); md[3] = fmaf(wid,s3,md[3]);
            bea = fmaf(wie,bs,bea); bda = fmaf(wid,bs,bda);
        }
        float* fp = fold_e + tid*5;
        fp[0]=me[0]; fp[1]=me[1]; fp[2]=me[2]; fp[3]=me[3];
        fp[4] = bea + b_ih_e[tid] + b_hh_e[tid];
        float* fq = fold_d + tid*5;
        fq[0]=md[0]; fq[1]=md[1]; fq[2]=md[2]; fq[3]=md[3];
        fq[4] = bda + b_ih_d[tid] + b_hh_d[tid];
    }

    // ---- staging: load raw (also passthrough to out_expert), zero H ----
    {
        const int base = b0g * (TT*4);
        for (int idx = tid; idx < RR*TT*4; idx += 256) {
            float v = expert[base + idx];
            sRaw[idx] = v;
            out_expert[base + idx] = v;
        }
        u32* hz = (u32*)Hbuf;
        for (int idx = tid; idx < HBUF_U16; idx += 256) hz[idx] = 0;   // both buffers (2*1664 u16 = 1664 u32*2? -> loop below)
        for (int idx = tid; idx < HBUF_U16; idx += 256) hz[HBUF_U16 + idx] = 0; // note: u32 indexing covers 2 u16 each
        __syncthreads();
        // rel-xy transform -> inp (bf16); x_0 into Hbuf0; K-col 68 = 1.0 in both buffers
        for (int idx = tid; idx < RR*TT*4; idx += 256) {
            int q = idx % (TT*4);
            int k = q & 3, t = q >> 2;
            int row = idx / (TT*4);
            float v = sRaw[idx];
            if (k < 2 && t > 0) v -= sRaw[idx - 4];
            u16 hv = f2bf(v);
            inp[idx] = hv;
            if (t == 0) Hbuf[row*HST + 64 + k] = hv;
            if (q == 0) {
                Hbuf[row*HST + 68] = 0x3F80;                // 1.0
                Hbuf[HBUF_U16 + row*HST + 68] = 0x3F80;
            }
        }
        __syncthreads();
    }

    float creg[4] = {0.f, 0.f, 0.f, 0.f};
    bf16x8 bw[4][3];

    // build encoder B-fragments (W_hh rows + folded-K tail)
    auto build_bw = [&](const float* Whh, const float* fold) {
#pragma unroll
        for (int g = 0; g < 4; ++g) {
            const float* wr = Whh + (g*64 + jcol) * 64;
            bw[g][0] = packw(wr + quad*8);
            bw[g][1] = packw(wr + 32 + quad*8);
            bf16x8 t;
#pragma unroll
            for (int j = 0; j < 8; ++j) t[j] = 0;
            if (quad == 0) {
                const float* fp = fold + (g*64 + jcol) * 5;
#pragma unroll
                for (int j = 0; j < 4; ++j) t[j] = (short)f2bf(fp[j]);
                t[4] = (short)f2bf(fp[4]);
            }
            bw[g][2] = t;
        }
    };

    // one LSTM step: MFMA K=96 (h | x | 1 | 0-pad) + fused-denominator gate math
    auto lstm_step = [&](const u16* Hc, u16* Hn) {
        bf16x8 a0 = *(const bf16x8*)(Hc + lcol*HST + quad*8);
        bf16x8 a1 = *(const bf16x8*)(Hc + lcol*HST + 32 + quad*8);
        bf16x8 a2 = *(const bf16x8*)(Hc + lcol*HST + 64 + quad*8);
        f32x4 acc[4];
#pragma unroll
        for (int g = 0; g < 4; ++g) {
            f32x4 z = {0.f, 0.f, 0.f, 0.f};
            z = mfma16(a0, bw[g][0], z);
            z = mfma16(a1, bw[g][1], z);
            acc[g] = mfma16(a2, bw[g][2], z);
        }
#pragma unroll
        for (int r = 0; r < 4; ++r) {
            float ig = acc[0][r], fg = acc[1][r], gg = acc[2][r], og = acc[3][r];
            float Ei = __expf(-ig);
            float Ef = __expf(-fg);
            float Eg = __expf(-2.f * gg);
            float P = (1.f + Ei) * (1.f + Eg);
            float Q = 1.f + Ef;
            float num = fmaf(creg[r] * P, Ef, (1.f - Eg) * Q);
            float c = num * rcpf(P * Q);
            creg[r] = c;
            float Ec = __expf(-2.f * c);
            float Eo = __expf(-og);
            float h = (1.f - Ec) * rcpf((1.f + Eo) * (1.f + Ec));
            Hn[(quad*4 + r)*HST + jcol] = f2bf(h);
        }
    };

    // ---- encoder ----
    build_bw(W_hh_e, fold_e);
    for (int stp = 0; stp < TT; ++stp) {
        const u16* Hc = Hbuf + (stp & 1) * HBUF_U16;
        u16* Hn = Hbuf + ((stp + 1) & 1) * HBUF_U16;
        lstm_step(Hc, Hn);
        if (tid < 64 && stp < TT-1) {
            int row = tid >> 2, k = tid & 3;
            Hn[row*HST + 64 + k] = inp[row*(TT*4) + (stp+1)*4 + k];
        }
        __syncthreads();
    }
    // hT in Hbuf[0] (TT even)

    // zero zBuf pad (written regions overwritten later; pad k>=100 must stay 0)
    {
        u32* zb = (u32*)zBuf;
        for (int idx = tid; idx < RR*136/2; idx += 256) zb[idx] = 0;
    }

    auto mlp_hidden = [&](const u16* inB, int inStride, u16* outB,
                          const float* Wg, const float* bg) {
        float bv = bg[jcol];
        bf16x8 bb0 = packw(Wg + jcol*64 + quad*8);
        bf16x8 bb1 = packw(Wg + jcol*64 + 32 + quad*8);
        f32x4 acc = {bv, bv, bv, bv};
        bf16x8 a0 = *(const bf16x8*)(inB + lcol*inStride + quad*8);
        bf16x8 a1 = *(const bf16x8*)(inB + lcol*inStride + 32 + quad*8);
        acc = mfma16(a0, bb0, acc);
        acc = mfma16(a1, bb1, acc);
#pragma unroll
        for (int r = 0; r < 4; ++r)
            outB[(quad*4 + r)*72 + jcol] = f2bf(leaky(acc[r]));
        __syncthreads();
    };

    auto mlp_final = [&](const u16* inB, const float* Wg, const float* bg, int mode) {
#pragma unroll
        for (int ni = 0; ni < 2; ++ni) {
            int nt = wv + ni*4;
            if (nt >= 7) continue;
            int n = nt*16 + lcol;
            bool ok = (n < LL);
            float bv = ok ? bg[n] : 0.f;
            bf16x8 bb0, bb1;
            if (ok) {
                bb0 = packw(Wg + n*64 + quad*8);
                bb1 = packw(Wg + n*64 + 32 + quad*8);
            } else {
#pragma unroll
                for (int j = 0; j < 8; ++j) { bb0[j] = 0; bb1[j] = 0; }
            }
            f32x4 acc = {bv, bv, bv, bv};
            bf16x8 a0 = *(const bf16x8*)(inB + lcol*72 + quad*8);
            bf16x8 a1 = *(const bf16x8*)(inB + lcol*72 + 32 + quad*8);
            acc = mfma16(a0, bb0, acc);
            acc = mfma16(a1, bb1, acc);
            if (ok) {
#pragma unroll
                for (int r = 0; r < 4; ++r) {
                    int m = quad*4 + r;
                    float vv = leaky(acc[r]);
                    size_t gi = (size_t)(b0g + m) * LL + n;
                    if (mode == 0) {
                        muBuf[m*LL + n] = vv;
                        out_mu[gi] = vv;
                    } else {
                        out_lv[gi] = vv;
                        float zv = tanh_(fmaf(eps[gi], __expf(0.5f * vv), muBuf[m*LL + n]));
                        zBuf[m*136 + n] = f2bf(zv);
                    }
                }
            }
        }
        __syncthreads();
    };

    // mean path (reads hT from Hbuf stride HST)
    mlp_hidden(Hbuf, HST, XB0, mean_Ws, mean_bs);
    mlp_hidden(XB0, 72, XB1, mean_Ws + 4096, mean_bs + 64);
    mlp_hidden(XB1, 72, XB0, mean_Ws + 8192, mean_bs + 128);
    mlp_final(XB0, mean_Wf, mean_bf, 0);
    // logvar path + fused reparameterization
    mlp_hidden(Hbuf, HST, XB0, lv_Ws, lv_bs);
    mlp_hidden(XB0, 72, XB1, lv_Ws + 4096, lv_bs + 64);
    mlp_hidden(XB1, 72, XB0, lv_Ws + 8192, lv_bs + 128);
    mlp_final(XB0, lv_Wf, lv_bf, 1);

    // ---- dh = z @ W_init^T + b_init -> Hbuf[0] h-cols + creg; decoder prep ----
    {
        float bv = b_init[jcol];
        bf16x8 bi[4];
#pragma unroll
        for (int kt = 0; kt < 3; ++kt)
            bi[kt] = packw(W_init + jcol*LL + kt*32 + quad*8);
        {
            float f[8];
#pragma unroll
            for (int j = 0; j < 8; ++j) {
                int k = 96 + quad*8 + j;
                f[j] = (k < LL) ? W_init[jcol*LL + k] : 0.f;
            }
            bi[3] = packw(f);
        }
        f32x4 acc = {bv, bv, bv, bv};
#pragma unroll
        for (int kt = 0; kt < 4; ++kt) {
            bf16x8 az = *(const bf16x8*)(zBuf + lcol*136 + kt*32 + quad*8);
            acc = mfma16(az, bi[kt], acc);
        }
#pragma unroll
        for (int r = 0; r < 4; ++r) {
            creg[r] = acc[r];
            Hbuf[(quad*4 + r)*HST + jcol] = f2bf(acc[r]);
        }
        // decoder x_0 = init_state into Hbuf0 cols 64..67 (+ fp32 sPrev)
        if (tid < RR*4) {
            float v = init_state[b0g*4 + tid];
            sPrev[tid] = v;
            Hbuf[(tid >> 2)*HST + 64 + (tid & 3)] = f2bf(v);
        }
        if (tid < 128) sWc[tid] = W_c[tid];
        __syncthreads();
    }

    build_bw(W_hh_d, fold_d);
    const float bc0 = b_c[0], bc1 = b_c[1];

    // ---- decoder ----
    for (int stp = 0; stp < TT; ++stp) {
        const u16* Hc = Hbuf + (stp & 1) * HBUF_U16;
        u16* Hn = Hbuf + ((stp + 1) & 1) * HBUF_U16;
        lstm_step(Hc, Hn);
        __syncthreads();
        if (tid < 64) {
            int row = tid >> 2, kq = tid & 3;
            const u16* hr = Hn + row*HST + kq*16;
            bf16x8 h0 = *(const bf16x8*)(hr);
            bf16x8 h1 = *(const bf16x8*)(hr + 8);
            const float4* w0 = (const float4*)(sWc + kq*16);
            const float4* w1 = (const float4*)(sWc + 64 + kq*16);
            float a0 = 0.f, a1 = 0.f;
#pragma unroll
            for (int p = 0; p < 2; ++p) {
                float4 wa = w0[2*p], wb = w0[2*p+1];
                float4 va = w1[2*p], vb = w1[2*p+1];
                bf16x8 hh = p ? h1 : h0;
                float hf[8];
#pragma unroll
                for (int j = 0; j < 8; ++j) hf[j] = bf2f((u16)hh[j]);
                a0 = fmaf(hf[0], wa.x, a0); a0 = fmaf(hf[1], wa.y, a0);
                a0 = fmaf(hf[2], wa.z, a0); a0 = fmaf(hf[3], wa.w, a0);
                a0 = fmaf(hf[4], wb.x, a0); a0 = fmaf(hf[5], wb.y, a0);
                a0 = fmaf(hf[6], wb.z, a0); a0 = fmaf(hf[7], wb.w, a0);
                a1 = fmaf(hf[0], va.x, a1); a1 = fmaf(hf[1], va.y, a1);
                a1 = fmaf(hf[2], va.z, a1); a1 = fmaf(hf[3], va.w, a1);
                a1 = fmaf(hf[4], vb.x, a1); a1 = fmaf(hf[5], vb.y, a1);
                a1 = fmaf(hf[6], vb.z, a1); a1 = fmaf(hf[7], vb.w, a1);
            }
            a0 += __shfl_xor(a0, 1); a1 += __shfl_xor(a1, 1);
            a0 += __shfl_xor(a0, 2); a1 += __shfl_xor(a1, 2);
            if (kq == 0) {
                float pedal = a0 + bc0;
                float steer = fminf(fmaxf(a1 + bc1, -0.5f), 0.5f);
                float4 pv = *(const float4*)(sPrev + row*4);
                float x = pv.x, y = pv.y, psi = pv.z, v = pv.w;
                float v1 = fminf(fmaxf(v + pedal * DTC, 0.f), 30.f);
                float sn, cs;
                __sincosf(psi, &sn, &cs);
                float psid = fminf(fmaxf(v * __tanf(steer) * 0.4f, -1.57f), 1.57f);
                float nx = fmaf(v * cs, DTC, x);
                float ny = fmaf(v * sn, DTC, y);
                float npsi = fmaf(psid, DTC, psi);
                float4 o; o.x = nx; o.y = ny; o.z = npsi; o.w = v1;
                *(float4*)(sPrev + row*4) = o;
                *(float4*)(out_recons + ((size_t)(b0g + row) * TT + stp) * 4) = o;
                // next-step x into Hn cols 64..67 (bf16, 8B write)
                u32 lo = (u32)f2bf(nx) | ((u32)f2bf(ny) << 16);
                u32 hi = (u32)f2bf(npsi) | ((u32)f2bf(v1) << 16);
                uint2 pk; pk.x = lo; pk.y = hi;
                *(uint2*)(Hn + row*HST + 64) = pk;
            }
        }
        __syncthreads();
    }
}

extern "C" void kernel_launch(void* const* d_in, const int* in_sizes, int n_in,
                              void* d_out, int out_size, void* d_ws, size_t ws_size,
                              hipStream_t stream) {
    (void)in_sizes; (void)n_in; (void)ws_size; (void)d_ws; (void)out_size;
    const float* expert    = (const float*)d_in[0];
    const float* init_st   = (const float*)d_in[1];
    const float* eps       = (const float*)d_in[2];
    const float* W_se      = (const float*)d_in[3];
    const float* b_se      = (const float*)d_in[4];
    const float* W_ih_e    = (const float*)d_in[5];
    const float* W_hh_e    = (const float*)d_in[6];
    const float* b_ih_e    = (const float*)d_in[7];
    const float* b_hh_e    = (const float*)d_in[8];
    const float* mean_Ws   = (const float*)d_in[9];
    const float* mean_bs   = (const float*)d_in[10];
    const float* mean_Wf   = (const float*)d_in[11];
    const float* mean_bf   = (const float*)d_in[12];
    const float* lv_Ws     = (const float*)d_in[13];
    const float* lv_bs     = (const float*)d_in[14];
    const float* lv_Wf     = (const float*)d_in[15];
    const float* lv_bf     = (const float*)d_in[16];
    const float* W_init    = (const float*)d_in[17];
    const float* b_init    = (const float*)d_in[18];
    const float* W_ih_d    = (const float*)d_in[19];
    const float* W_hh_d    = (const float*)d_in[20];
    const float* b_ih_d    = (const float*)d_in[21];
    const float* b_hh_d    = (const float*)d_in[22];
    const float* W_c       = (const float*)d_in[23];
    const float* b_c       = (const float*)d_in[24];

    float* out = (float*)d_out;
    const size_t n_traj = (size_t)B_TOT * TT * 4;
    const size_t n_lat  = (size_t)B_TOT * LL;
    float* out_recons = out;
    float* out_expert = out + n_traj;
    float* out_mu     = out + 2 * n_traj;
    float* out_lv     = out + 2 * n_traj + n_lat;

    vae_lstm_kernel<<<NBLK, 256, 0, stream>>>(
        expert, init_st, eps, W_se, b_se, W_ih_e, W_hh_e, b_ih_e, b_hh_e,
        mean_Ws, mean_bs, mean_Wf, mean_bf, lv_Ws, lv_bs, lv_Wf, lv_bf,
        W_init, b_init, W_ih_d, W_hh_d, b_ih_d, b_hh_d, W_c, b_c,
        out_recons, out_expert, out_mu, out_lv);
}